// Round 2
// baseline (541.338 us; speedup 1.0000x reference)
//
#include <hip/hip_runtime.h>
#include <hip/hip_bf16.h>

// Problem constants
#define B_  32
#define T_  1500
#define E_  512
#define A_  512
#define C_  10
#define KH  100      // conv half-width
#define KW  201      // conv width
#define O_  512
#define M_  (B_*T_)  // 48000 rows
#define KP  544      // K' = 512 (enc) + 32 (conv padded)
#define SCALING_ 2.0f
#define BT_BYTES 17408   // one staged B tile: 16 cols x 544 k x 2B

typedef __bf16 bf16;
typedef __attribute__((ext_vector_type(8))) __bf16 bf16x8;
typedef __attribute__((ext_vector_type(4))) float f32x4;

__device__ __forceinline__ void load_lds16(const void* g, void* l) {
    // 16B per lane; LDS dest = wave-uniform base + lane*16 (HW behavior)
    __builtin_amdgcn_global_load_lds(
        (const __attribute__((address_space(1))) unsigned int*)g,
        (__attribute__((address_space(3))) unsigned int*)l,
        16, 0, 0);
}

// ---------------- prep: bias[b][a] = b_enc[a] + dec_z[b,:] @ W_dec[:,a] ----------------
__global__ void prep_bias(const float* __restrict__ dec_z, const float* __restrict__ W_dec,
                          const float* __restrict__ b_enc, float* __restrict__ bias) {
    int idx = blockIdx.x * 256 + threadIdx.x;   // [0, 16384)
    int b = idx >> 9, a = idx & 511;
    float acc = b_enc[a];
#pragma unroll 8
    for (int d = 0; d < 512; ++d)
        acc += dec_z[b * 512 + d] * W_dec[d * 512 + a];
    bias[idx] = acc;
}

// ---------------- prep: wt[a][k] bf16, k<512: W_enc[k][a]; 512<=k<522: W_att[k-512][a]; else 0
__global__ void prep_wt(const float* __restrict__ W_enc, const float* __restrict__ W_att,
                        bf16* __restrict__ wt) {
    int k = blockIdx.x;            // [0, 544)
    for (int a = threadIdx.x; a < 512; a += 256) {
        float v;
        if (k < 512)       v = W_enc[k * 512 + a];
        else if (k < 522)  v = W_att[(k - 512) * 512 + a];
        else               v = 0.0f;
        wt[a * KP + k] = (bf16)v;
    }
}

// ---------------- prep: convpad[row][0..9] = conv(att_prev)[b, :, t], rest of 32 = 0 -----
__global__ void prep_conv(const float* __restrict__ att_prev, const float* __restrict__ conv_w,
                          bf16* __restrict__ convpad) {
    int tc = blockIdx.x;   // 6 chunks of 256 t's
    int b  = blockIdx.y;   // 32
    int tid = threadIdx.x;
    __shared__ float s_att[456];
    __shared__ float s_w[C_ * KW];   // 2010
    int t0 = tc * 256;
    for (int i = tid; i < 456; i += 256) {
        int ti = t0 - KH + i;
        s_att[i] = (ti >= 0 && ti < T_) ? att_prev[b * T_ + ti] : 0.0f;
    }
    for (int i = tid; i < C_ * KW; i += 256) s_w[i] = conv_w[i];
    __syncthreads();
    int t = t0 + tid;
    if (t < T_) {
        float acc[C_];
#pragma unroll
        for (int c = 0; c < C_; ++c) acc[c] = 0.0f;
        for (int j = 0; j < KW; ++j) {
            float a = s_att[tid + j];
#pragma unroll
            for (int c = 0; c < C_; ++c) acc[c] += a * s_w[c * KW + j];
        }
        bf16* dst = convpad + (size_t)(b * T_ + t) * 32;
#pragma unroll
        for (int c = 0; c < C_; ++c) dst[c] = (bf16)acc[c];
#pragma unroll
        for (int c = C_; c < 32; ++c) dst[c] = (bf16)0.0f;
    }
}

// ---------------- main fused GEMM: e[row] = gvec . tanh(enc@W_enc + conv@W_att + bias) -----
// 4 waves/block, 128 rows/block (wave = 2 M-tiles of 16 rows), K'=544 (17 k-steps)
// A-frags in registers; B staged to LDS (double-buffered global_load_lds)
__global__ __launch_bounds__(256, 2) void main_gemm(
        const float* __restrict__ enc, const bf16* __restrict__ convpad,
        const bf16* __restrict__ wt, const float* __restrict__ bias,
        const float* __restrict__ gvec, float* __restrict__ e_out) {
    __shared__ __align__(16) char b_lds[2 * BT_BYTES];   // 34816 B
    const int tid  = threadIdx.x;
    const int lane = tid & 63;
    const int wid  = tid >> 6;
    const int g    = lane >> 4;       // 0..3 (k-group / D row-group)
    const int c15  = lane & 15;       // A-row / B-col within tile
    const int rowbase = blockIdx.x * 128 + wid * 32;   // wave's rows: rowbase..rowbase+31

    // ---- A-frags: 2 tiles x 16 ksteps, direct global f32 -> bf16 regs ----
    bf16x8 afrag[2][16];
#pragma unroll
    for (int m = 0; m < 2; ++m) {
        const float* ap = enc + (size_t)(rowbase + m * 16 + c15) * 512 + g * 8;
#pragma unroll 4
        for (int kt = 0; kt < 16; ++kt) {
            float4 f0 = *(const float4*)(ap + kt * 32);
            float4 f1 = *(const float4*)(ap + kt * 32 + 4);
            bf16x8 v;
            v[0] = (bf16)f0.x; v[1] = (bf16)f0.y; v[2] = (bf16)f0.z; v[3] = (bf16)f0.w;
            v[4] = (bf16)f1.x; v[5] = (bf16)f1.y; v[6] = (bf16)f1.z; v[7] = (bf16)f1.w;
            afrag[m][kt] = v;
        }
    }
    // conv A-frags (k-step 16)
    bf16x8 acv[2];
#pragma unroll
    for (int m = 0; m < 2; ++m)
        acv[m] = *(const bf16x8*)(convpad + (size_t)(rowbase + m * 16 + c15) * 32 + g * 8);

    // bias row offsets for D rows (row = rowbase + m*16 + g*4 + r)
    int brw[2][4];
#pragma unroll
    for (int m = 0; m < 2; ++m)
#pragma unroll
        for (int r = 0; r < 4; ++r)
            brw[m][r] = ((rowbase + m * 16 + g * 4 + r) / T_) * 512;

    // ---- stage B tile 0 into buf 0 ----
    {
        const bf16* src = wt;   // nt = 0
#pragma unroll
        for (int p = 0; p < 4; ++p) {
            int c = wid + p * 4;
            load_lds16(src + c * 512 + lane * 8, b_lds + c * 1024);
        }
        if (wid == 0) load_lds16(src + 16 * 512 + lane * 8, b_lds + 16 * 1024);
    }

    float s[2][4] = {{0.f,0.f,0.f,0.f},{0.f,0.f,0.f,0.f}};

    for (int nt = 0; nt < 32; ++nt) {
        __syncthreads();   // drains vmcnt: B[nt] resident; all waves done with B[nt-1]
        if (nt < 31) {
            const bf16* src = wt + (size_t)(nt + 1) * 16 * KP;
            char* dst = b_lds + ((nt + 1) & 1) * BT_BYTES;
#pragma unroll
            for (int p = 0; p < 4; ++p) {
                int c = wid + p * 4;
                load_lds16(src + c * 512 + lane * 8, dst + c * 1024);
            }
            if (wid == 0) load_lds16(src + 16 * 512 + lane * 8, dst + 16 * 1024);
        }
        const char* bb = b_lds + (nt & 1) * BT_BYTES + c15 * 1088 + g * 16;
        f32x4 acc0 = {0.f, 0.f, 0.f, 0.f};
        f32x4 acc1 = {0.f, 0.f, 0.f, 0.f};
#pragma unroll
        for (int kt = 0; kt < 16; ++kt) {
            bf16x8 bv = *(const bf16x8*)(bb + kt * 64);
            acc0 = __builtin_amdgcn_mfma_f32_16x16x32_bf16(afrag[0][kt], bv, acc0, 0, 0, 0);
            acc1 = __builtin_amdgcn_mfma_f32_16x16x32_bf16(afrag[1][kt], bv, acc1, 0, 0, 0);
        }
        {   // conv k-step (k = 512..543)
            bf16x8 bv = *(const bf16x8*)(bb + 1024);
            acc0 = __builtin_amdgcn_mfma_f32_16x16x32_bf16(acv[0], bv, acc0, 0, 0, 0);
            acc1 = __builtin_amdgcn_mfma_f32_16x16x32_bf16(acv[1], bv, acc1, 0, 0, 0);
        }
        int n = nt * 16 + c15;
        float gv = gvec[n];
#pragma unroll
        for (int m = 0; m < 2; ++m) {
            f32x4 a = m ? acc1 : acc0;
#pragma unroll
            for (int r = 0; r < 4; ++r) {
                float x  = a[r] + bias[brw[m][r] + n];
                float ex = __expf(2.0f * x);                      // exp(2x)
                float th = 1.0f - __fdividef(2.0f, ex + 1.0f);    // tanh(x)
                s[m][r] += gv * th;
            }
        }
    }
    // reduce over the 16 lanes sharing the same D rows (xor within c15)
#pragma unroll
    for (int msk = 1; msk < 16; msk <<= 1)
#pragma unroll
        for (int m = 0; m < 2; ++m)
#pragma unroll
            for (int r = 0; r < 4; ++r)
                s[m][r] += __shfl_xor(s[m][r], msk, 64);
    if (c15 == 0) {
#pragma unroll
        for (int m = 0; m < 2; ++m)
#pragma unroll
            for (int r = 0; r < 4; ++r)
                e_out[rowbase + m * 16 + g * 4 + r] = s[m][r];
    }
}

// ---------------- softmax over T per batch: w = softmax(SCALING * e) ----------------
__global__ void softmax_k(const float* __restrict__ e_in, float* __restrict__ w_out) {
    int b = blockIdx.x, tid = threadIdx.x;
    __shared__ float red[256];
    float v[6];
    float mx = -1e30f;
#pragma unroll
    for (int i = 0; i < 6; ++i) {
        int t = i * 256 + tid;
        v[i] = (t < T_) ? SCALING_ * e_in[b * T_ + t] : -1e30f;
        mx = fmaxf(mx, v[i]);
    }
    red[tid] = mx; __syncthreads();
    for (int st = 128; st > 0; st >>= 1) {
        if (tid < st) red[tid] = fmaxf(red[tid], red[tid + st]);
        __syncthreads();
    }
    mx = red[0]; __syncthreads();
    float sum = 0.f;
#pragma unroll
    for (int i = 0; i < 6; ++i) { v[i] = __expf(v[i] - mx); sum += v[i]; }
    red[tid] = sum; __syncthreads();
    for (int st = 128; st > 0; st >>= 1) {
        if (tid < st) red[tid] += red[tid + st];
        __syncthreads();
    }
    float inv = 1.0f / red[0];
#pragma unroll
    for (int i = 0; i < 6; ++i) {
        int t = i * 256 + tid;
        if (t < T_) w_out[b * T_ + t] = v[i] * inv;
    }
}

// ---------------- context partial: partial[ty][b][e] = sum_{t in chunk} w[b,t] enc[b,t,e] --
__global__ void ctx_partial(const float* __restrict__ enc, const float* __restrict__ w,
                            float* __restrict__ partial) {
    int e  = blockIdx.x * 256 + threadIdx.x;   // gridDim.x = 2
    int ty = blockIdx.y;                        // 16
    int b  = blockIdx.z;                        // 32
    int t0 = ty * 94;
    int t1 = min(t0 + 94, T_);
    float acc = 0.f;
#pragma unroll 8
    for (int t = t0; t < t1; ++t)
        acc += w[b * T_ + t] * enc[((size_t)b * T_ + t) * 512 + e];
    partial[(ty * 32 + b) * 512 + e] = acc;
}

// ---------------- output proj: c[b] = (sum partials) @ W_o + b_o ----------------
__global__ void out_proj(const float* __restrict__ partial, const float* __restrict__ Wo,
                         const float* __restrict__ bo, float* __restrict__ out) {
    int b = blockIdx.x, tid = threadIdx.x;
    __shared__ float ctx[512];
    for (int e = tid; e < 512; e += 256) {
        float s = 0.f;
#pragma unroll
        for (int p = 0; p < 16; ++p) s += partial[(p * 32 + b) * 512 + e];
        ctx[e] = s;
    }
    __syncthreads();
    float a0 = bo[tid];
    float a1 = bo[tid + 256];
#pragma unroll 8
    for (int e = 0; e < 512; ++e) {
        float c = ctx[e];
        a0 += c * Wo[e * 512 + tid];
        a1 += c * Wo[e * 512 + tid + 256];
    }
    out[b * 512 + tid]       = a0;
    out[b * 512 + tid + 256] = a1;
}

extern "C" void kernel_launch(void* const* d_in, const int* in_sizes, int n_in,
                              void* d_out, int out_size, void* d_ws, size_t ws_size,
                              hipStream_t stream) {
    const float* enc      = (const float*)d_in[0];
    // d_in[1] = enc_len (unused: all rows are full length T)
    const float* dec_z    = (const float*)d_in[2];
    const float* att_prev = (const float*)d_in[3];
    const float* W_enc    = (const float*)d_in[4];
    const float* b_enc    = (const float*)d_in[5];
    const float* W_dec    = (const float*)d_in[6];
    const float* W_att    = (const float*)d_in[7];
    const float* conv_w   = (const float*)d_in[8];
    const float* gvec     = (const float*)d_in[9];
    const float* W_o      = (const float*)d_in[10];
    const float* b_o      = (const float*)d_in[11];

    // workspace layout (bytes); partial aliases bias+e_buf (dead by ctx_partial time):
    //   [0, 65536)             bias     f32 [32][512]        (main_gemm input)
    //   [65536, 257536)        e_buf    f32 [48000]          (softmax input)
    //   [0, 1048576)           partial  f32 [16][32][512]    (written AFTER both are dead)
    //   [1048576, 4120576)     convpad  bf16 [48000][32]
    //   [4120576, 4677632)     wt       bf16 [512][544]
    char* ws = (char*)d_ws;
    float* bias    = (float*)(ws);
    float* e_buf   = (float*)(ws + 65536);
    float* partial = (float*)(ws);
    bf16*  convpad = (bf16*)(ws + 1048576);
    bf16*  wt      = (bf16*)(ws + 4120576);

    float* c_out = (float*)d_out;           // [32][512]
    float* w_out = c_out + B_ * O_;         // [32][1500]

    prep_bias<<<64, 256, 0, stream>>>(dec_z, W_dec, b_enc, bias);
    prep_wt<<<KP, 256, 0, stream>>>(W_enc, W_att, wt);
    prep_conv<<<dim3(6, B_), 256, 0, stream>>>(att_prev, conv_w, convpad);
    main_gemm<<<M_ / 128, 256, 0, stream>>>(enc, convpad, wt, bias, gvec, e_buf);
    softmax_k<<<B_, 256, 0, stream>>>(e_buf, w_out);
    ctx_partial<<<dim3(2, 16, B_), 256, 0, stream>>>(enc, w_out, partial);
    out_proj<<<B_, 256, 0, stream>>>(partial, W_o, b_o, c_out);
}

// Round 3
// 334.561 us; speedup vs baseline: 1.6181x; 1.6181x over previous
//
#include <hip/hip_runtime.h>
#include <hip/hip_bf16.h>

// Problem constants
#define B_  32
#define T_  1500
#define E_  512
#define A_  512
#define C_  10
#define KH  100      // conv half-width
#define KW  201      // conv width
#define O_  512
#define M_  (B_*T_)  // 48000 rows
#define KP  544      // K' = 512 (enc) + 32 (conv padded)
#define SCALING_ 2.0f
#define BT_BYTES 17408   // one staged B tile: 16 cols x 544 k x 2B (k-major chunks)

typedef __bf16 bf16;
typedef __attribute__((ext_vector_type(8))) __bf16 bf16x8;
typedef __attribute__((ext_vector_type(4))) float f32x4;

__device__ __forceinline__ void load_lds16(const void* g, void* l) {
    // 16B per lane; LDS dest = wave-uniform base + lane*16 (HW behavior)
    __builtin_amdgcn_global_load_lds(
        (const __attribute__((address_space(1))) unsigned int*)g,
        (__attribute__((address_space(3))) unsigned int*)l,
        16, 0, 0);
}

// ---------------- prep: bias[b][a] = b_enc[a] + dec_z[b,:] @ W_dec[:,a] ----------------
__global__ void prep_bias(const float* __restrict__ dec_z, const float* __restrict__ W_dec,
                          const float* __restrict__ b_enc, float* __restrict__ bias) {
    int idx = blockIdx.x * 256 + threadIdx.x;   // [0, 16384)
    int b = idx >> 9, a = idx & 511;
    float acc = b_enc[a];
#pragma unroll 8
    for (int d = 0; d < 512; ++d)
        acc += dec_z[b * 512 + d] * W_dec[d * 512 + a];
    bias[idx] = acc;
}

// ---------------- prep: wt2 k-major-tiled bf16 weight: wt2[nt][s][c][j]
// element (a = nt*16+c, k = s*8+j):  k<512 -> W_enc[k][a]; 512<=k<522 -> W_att[k-512][a]; else 0
__global__ void prep_wt(const float* __restrict__ W_enc, const float* __restrict__ W_att,
                        bf16* __restrict__ wt2) {
    int k = blockIdx.x;            // [0, 544)
    int s = k >> 3, j = k & 7;
    for (int a = threadIdx.x; a < 512; a += 256) {
        float v;
        if (k < 512)       v = W_enc[k * 512 + a];
        else if (k < 522)  v = W_att[(k - 512) * 512 + a];
        else               v = 0.0f;
        int nt = a >> 4, c = a & 15;
        wt2[((nt * 68 + s) * 16 + c) * 8 + j] = (bf16)v;
    }
}

// ---------------- prep: convpad[row][0..9] = conv(att_prev)[b, :, t], rest of 32 = 0 -----
__global__ void prep_conv(const float* __restrict__ att_prev, const float* __restrict__ conv_w,
                          bf16* __restrict__ convpad) {
    int tc = blockIdx.x;   // 6 chunks of 256 t's
    int b  = blockIdx.y;   // 32
    int tid = threadIdx.x;
    __shared__ float s_att[456];
    __shared__ float s_w[C_ * KW];   // 2010
    int t0 = tc * 256;
    for (int i = tid; i < 456; i += 256) {
        int ti = t0 - KH + i;
        s_att[i] = (ti >= 0 && ti < T_) ? att_prev[b * T_ + ti] : 0.0f;
    }
    for (int i = tid; i < C_ * KW; i += 256) s_w[i] = conv_w[i];
    __syncthreads();
    int t = t0 + tid;
    if (t < T_) {
        float acc[C_];
#pragma unroll
        for (int c = 0; c < C_; ++c) acc[c] = 0.0f;
        for (int j = 0; j < KW; ++j) {
            float a = s_att[tid + j];
#pragma unroll
            for (int c = 0; c < C_; ++c) acc[c] += a * s_w[c * KW + j];
        }
        bf16* dst = convpad + (size_t)(b * T_ + t) * 32;
#pragma unroll
        for (int c = 0; c < C_; ++c) dst[c] = (bf16)acc[c];
#pragma unroll
        for (int c = C_; c < 32; ++c) dst[c] = (bf16)0.0f;
    }
}

// ---------------- main fused GEMM: e[row] = gvec . tanh(enc@W_enc + conv@W_att + bias) -----
// 4 waves/block, 128 rows/block (wave = 2 M-tiles of 16 rows), K'=544 (17 k-steps)
// A-frags fully in registers (static indexing!); B double-buffered in LDS, k-major
// layout so ds_read_b128 is conflict-free (wave covers one contiguous 1024B span).
__global__ __launch_bounds__(256, 2) void main_gemm(
        const float* __restrict__ enc, const bf16* __restrict__ convpad,
        const bf16* __restrict__ wt2, const float* __restrict__ bias,
        const float* __restrict__ gvec, float* __restrict__ e_out) {
    __shared__ __align__(16) char b_lds[2 * BT_BYTES];   // 34816 B
    const int tid  = threadIdx.x;
    const int lane = tid & 63;
    const int wid  = tid >> 6;
    const int g    = lane >> 4;       // 0..3 (k-group / D row-group)
    const int c15  = lane & 15;       // A-row / B-col within tile
    const int rowbase = blockIdx.x * 128 + wid * 32;   // wave's rows: rowbase..rowbase+31

    // ---- A-frags: 2 tiles x 16 ksteps, direct global f32 -> bf16 regs (ALL static idx) ----
    bf16x8 afrag[2][16];
#pragma unroll
    for (int m = 0; m < 2; ++m) {
        const float* ap = enc + (size_t)(rowbase + m * 16 + c15) * 512 + g * 8;
#pragma unroll
        for (int kt = 0; kt < 16; ++kt) {
            float4 f0 = *(const float4*)(ap + kt * 32);
            float4 f1 = *(const float4*)(ap + kt * 32 + 4);
            bf16x8 v;
            v[0] = (bf16)f0.x; v[1] = (bf16)f0.y; v[2] = (bf16)f0.z; v[3] = (bf16)f0.w;
            v[4] = (bf16)f1.x; v[5] = (bf16)f1.y; v[6] = (bf16)f1.z; v[7] = (bf16)f1.w;
            afrag[m][kt] = v;
        }
    }
    // conv A-frags (k-step 16)
    bf16x8 acv[2];
#pragma unroll
    for (int m = 0; m < 2; ++m)
        acv[m] = *(const bf16x8*)(convpad + (size_t)(rowbase + m * 16 + c15) * 32 + g * 8);

    // bias row offsets for D rows (row = rowbase + m*16 + g*4 + r)
    int brw[2][4];
#pragma unroll
    for (int m = 0; m < 2; ++m)
#pragma unroll
        for (int r = 0; r < 4; ++r)
            brw[m][r] = ((rowbase + m * 16 + g * 4 + r) / T_) * 512;

    // ---- stage B tile 0 into buf 0 (linear 17408B copy, 17 chunks of 1024B) ----
    {
        const char* src = (const char*)wt2;
#pragma unroll
        for (int p = 0; p < 4; ++p) {
            int q = wid + p * 4;
            load_lds16(src + q * 1024 + lane * 16, b_lds + q * 1024);
        }
        if (wid == 0) load_lds16(src + 16 * 1024 + lane * 16, b_lds + 16 * 1024);
    }

    const int lane_off = g * 256 + c15 * 16;   // conflict-free read offset
    float s[2][4] = {{0.f,0.f,0.f,0.f},{0.f,0.f,0.f,0.f}};

    for (int nt = 0; nt < 32; ++nt) {
        __syncthreads();   // drains vmcnt: B[nt] resident; all waves done with B[nt-1]
        if (nt < 31) {
            const char* src = (const char*)wt2 + (size_t)(nt + 1) * BT_BYTES;
            char* dst = b_lds + ((nt + 1) & 1) * BT_BYTES;
#pragma unroll
            for (int p = 0; p < 4; ++p) {
                int q = wid + p * 4;
                load_lds16(src + q * 1024 + lane * 16, dst + q * 1024);
            }
            if (wid == 0) load_lds16(src + 16 * 1024 + lane * 16, dst + 16 * 1024);
        }
        const char* bb = b_lds + (nt & 1) * BT_BYTES + lane_off;
        f32x4 acc0 = {0.f, 0.f, 0.f, 0.f};
        f32x4 acc1 = {0.f, 0.f, 0.f, 0.f};
#pragma unroll
        for (int kt = 0; kt < 16; ++kt) {
            bf16x8 bv = *(const bf16x8*)(bb + kt * 1024);
            acc0 = __builtin_amdgcn_mfma_f32_16x16x32_bf16(afrag[0][kt], bv, acc0, 0, 0, 0);
            acc1 = __builtin_amdgcn_mfma_f32_16x16x32_bf16(afrag[1][kt], bv, acc1, 0, 0, 0);
        }
        {   // conv k-step (k = 512..543), slot 16
            bf16x8 bv = *(const bf16x8*)(bb + 16 * 1024);
            acc0 = __builtin_amdgcn_mfma_f32_16x16x32_bf16(acv[0], bv, acc0, 0, 0, 0);
            acc1 = __builtin_amdgcn_mfma_f32_16x16x32_bf16(acv[1], bv, acc1, 0, 0, 0);
        }
        int n = nt * 16 + c15;
        float gv = gvec[n];
#pragma unroll
        for (int m = 0; m < 2; ++m) {
            f32x4 a = m ? acc1 : acc0;
#pragma unroll
            for (int r = 0; r < 4; ++r) {
                float x  = a[r] + bias[brw[m][r] + n];
                float ex = __expf(2.0f * x);                      // exp(2x)
                float th = 1.0f - __fdividef(2.0f, ex + 1.0f);    // tanh(x)
                s[m][r] += gv * th;
            }
        }
    }
    // reduce over the 16 lanes sharing the same D rows (xor within c15 group)
#pragma unroll
    for (int msk = 1; msk < 16; msk <<= 1)
#pragma unroll
        for (int m = 0; m < 2; ++m)
#pragma unroll
            for (int r = 0; r < 4; ++r)
                s[m][r] += __shfl_xor(s[m][r], msk, 64);
    if (c15 == 0) {
#pragma unroll
        for (int m = 0; m < 2; ++m)
#pragma unroll
            for (int r = 0; r < 4; ++r)
                e_out[rowbase + m * 16 + g * 4 + r] = s[m][r];
    }
}

// ---------------- softmax over T per batch: w = softmax(SCALING * e) ----------------
__global__ void softmax_k(const float* __restrict__ e_in, float* __restrict__ w_out) {
    int b = blockIdx.x, tid = threadIdx.x;
    __shared__ float red[256];
    float v[6];
    float mx = -1e30f;
#pragma unroll
    for (int i = 0; i < 6; ++i) {
        int t = i * 256 + tid;
        v[i] = (t < T_) ? SCALING_ * e_in[b * T_ + t] : -1e30f;
        mx = fmaxf(mx, v[i]);
    }
    red[tid] = mx; __syncthreads();
    for (int st = 128; st > 0; st >>= 1) {
        if (tid < st) red[tid] = fmaxf(red[tid], red[tid + st]);
        __syncthreads();
    }
    mx = red[0]; __syncthreads();
    float sum = 0.f;
#pragma unroll
    for (int i = 0; i < 6; ++i) { v[i] = __expf(v[i] - mx); sum += v[i]; }
    red[tid] = sum; __syncthreads();
    for (int st = 128; st > 0; st >>= 1) {
        if (tid < st) red[tid] += red[tid + st];
        __syncthreads();
    }
    float inv = 1.0f / red[0];
#pragma unroll
    for (int i = 0; i < 6; ++i) {
        int t = i * 256 + tid;
        if (t < T_) w_out[b * T_ + t] = v[i] * inv;
    }
}

// ---------------- context partial: partial[ty][b][e] = sum_{t in chunk} w[b,t] enc[b,t,e] --
__global__ void ctx_partial(const float* __restrict__ enc, const float* __restrict__ w,
                            float* __restrict__ partial) {
    int e  = blockIdx.x * 256 + threadIdx.x;   // gridDim.x = 2
    int ty = blockIdx.y;                        // 16
    int b  = blockIdx.z;                        // 32
    int t0 = ty * 94;
    int t1 = min(t0 + 94, T_);
    float acc = 0.f;
#pragma unroll 8
    for (int t = t0; t < t1; ++t)
        acc += w[b * T_ + t] * enc[((size_t)b * T_ + t) * 512 + e];
    partial[(ty * 32 + b) * 512 + e] = acc;
}

// ---------------- output proj: c[b] = (sum partials) @ W_o + b_o ----------------
__global__ void out_proj(const float* __restrict__ partial, const float* __restrict__ Wo,
                         const float* __restrict__ bo, float* __restrict__ out) {
    int b = blockIdx.x, tid = threadIdx.x;
    __shared__ float ctx[512];
    for (int e = tid; e < 512; e += 256) {
        float s = 0.f;
#pragma unroll
        for (int p = 0; p < 16; ++p) s += partial[(p * 32 + b) * 512 + e];
        ctx[e] = s;
    }
    __syncthreads();
    float a0 = bo[tid];
    float a1 = bo[tid + 256];
#pragma unroll 8
    for (int e = 0; e < 512; ++e) {
        float c = ctx[e];
        a0 += c * Wo[e * 512 + tid];
        a1 += c * Wo[e * 512 + tid + 256];
    }
    out[b * 512 + tid]       = a0;
    out[b * 512 + tid + 256] = a1;
}

extern "C" void kernel_launch(void* const* d_in, const int* in_sizes, int n_in,
                              void* d_out, int out_size, void* d_ws, size_t ws_size,
                              hipStream_t stream) {
    const float* enc      = (const float*)d_in[0];
    // d_in[1] = enc_len (unused: all rows are full length T)
    const float* dec_z    = (const float*)d_in[2];
    const float* att_prev = (const float*)d_in[3];
    const float* W_enc    = (const float*)d_in[4];
    const float* b_enc    = (const float*)d_in[5];
    const float* W_dec    = (const float*)d_in[6];
    const float* W_att    = (const float*)d_in[7];
    const float* conv_w   = (const float*)d_in[8];
    const float* gvec     = (const float*)d_in[9];
    const float* W_o      = (const float*)d_in[10];
    const float* b_o      = (const float*)d_in[11];

    // workspace layout (bytes); partial aliases bias+e_buf (dead by ctx_partial time):
    //   [0, 65536)             bias     f32 [32][512]        (main_gemm input)
    //   [65536, 257536)        e_buf    f32 [48000]          (softmax input)
    //   [0, 1048576)           partial  f32 [16][32][512]    (written AFTER both are dead)
    //   [1048576, 4120576)     convpad  bf16 [48000][32]
    //   [4120576, 4677632)     wt2      bf16 [32][68][16][8]
    char* ws = (char*)d_ws;
    float* bias    = (float*)(ws);
    float* e_buf   = (float*)(ws + 65536);
    float* partial = (float*)(ws);
    bf16*  convpad = (bf16*)(ws + 1048576);
    bf16*  wt2     = (bf16*)(ws + 4120576);

    float* c_out = (float*)d_out;           // [32][512]
    float* w_out = c_out + B_ * O_;         // [32][1500]

    prep_bias<<<64, 256, 0, stream>>>(dec_z, W_dec, b_enc, bias);
    prep_wt<<<KP, 256, 0, stream>>>(W_enc, W_att, wt2);
    prep_conv<<<dim3(6, B_), 256, 0, stream>>>(att_prev, conv_w, convpad);
    main_gemm<<<M_ / 128, 256, 0, stream>>>(enc, convpad, wt2, bias, gvec, e_buf);
    softmax_k<<<B_, 256, 0, stream>>>(e_buf, w_out);
    ctx_partial<<<dim3(2, 16, B_), 256, 0, stream>>>(enc, w_out, partial);
    out_proj<<<B_, 256, 0, stream>>>(partial, W_o, b_o, c_out);
}

// Round 4
// 316.562 us; speedup vs baseline: 1.7101x; 1.0569x over previous
//
#include <hip/hip_runtime.h>
#include <hip/hip_bf16.h>

// Problem constants
#define B_  32
#define T_  1500
#define C_  10
#define KH  100      // conv half-width
#define KW  201      // conv width
#define M_  48000
#define KP  544      // K' = 512 (enc) + 32 (conv padded)
#define SCALING_ 2.0f
#define BT_BYTES 17408   // one staged B tile: 16 cols x 544 k x 2B (k-major chunks)
#define C2L 2.8853900817779268f   // 2*log2(e)

typedef __bf16 bf16;
typedef __attribute__((ext_vector_type(8))) __bf16 bf16x8;
typedef __attribute__((ext_vector_type(4))) float f32x4;

__device__ __forceinline__ void load_lds16(const void* g, void* l) {
    __builtin_amdgcn_global_load_lds(
        (const __attribute__((address_space(1))) unsigned int*)g,
        (__attribute__((address_space(3))) unsigned int*)l,
        16, 0, 0);
}

// ---------------- prep: biasC[b][a] = (b_enc[a] + dec_z[b,:] @ W_dec[:,a]) * 2log2e ------
__global__ void prep_bias(const float* __restrict__ dec_z, const float* __restrict__ W_dec,
                          const float* __restrict__ b_enc, float* __restrict__ biasC) {
    int idx = blockIdx.x * 256 + threadIdx.x;   // [0, 16384)
    int b = idx >> 9, a = idx & 511;
    float acc = b_enc[a];
#pragma unroll 8
    for (int d = 0; d < 512; ++d)
        acc += dec_z[b * 512 + d] * W_dec[d * 512 + a];
    biasC[idx] = acc * C2L;
}

// ---------------- prep: gsum[h] = sum of gvec over n-half h ----------------
__global__ void gsum_k(const float* __restrict__ g, float* __restrict__ gsum) {
    __shared__ float red[256];
    int h = blockIdx.x, tid = threadIdx.x;
    red[tid] = g[h * 256 + tid];
    __syncthreads();
    for (int st = 128; st > 0; st >>= 1) {
        if (tid < st) red[tid] += red[tid + st];
        __syncthreads();
    }
    if (tid == 0) gsum[h] = red[0];
}

// ---------------- prep: wt2 k-major-tiled bf16 weight: wt2[nt][s][c][j] ----------------
__global__ void prep_wt(const float* __restrict__ W_enc, const float* __restrict__ W_att,
                        bf16* __restrict__ wt2) {
    int k = blockIdx.x;            // [0, 544)
    int s = k >> 3, j = k & 7;
    for (int a = threadIdx.x; a < 512; a += 256) {
        float v;
        if (k < 512)       v = W_enc[k * 512 + a];
        else if (k < 522)  v = W_att[(k - 512) * 512 + a];
        else               v = 0.0f;
        int nt = a >> 4, c = a & 15;
        wt2[((nt * 68 + s) * 16 + c) * 8 + j] = (bf16)v;
    }
}

// ---------------- prep: convpad[row][0..9] = conv(att_prev)[b, :, t], rest of 32 = 0 -----
__global__ void prep_conv(const float* __restrict__ att_prev, const float* __restrict__ conv_w,
                          bf16* __restrict__ convpad) {
    int tc = blockIdx.x;   // 6 chunks of 256 t's
    int b  = blockIdx.y;   // 32
    int tid = threadIdx.x;
    __shared__ float s_att[456];
    __shared__ float s_w[C_ * KW];   // 2010
    int t0 = tc * 256;
    for (int i = tid; i < 456; i += 256) {
        int ti = t0 - KH + i;
        s_att[i] = (ti >= 0 && ti < T_) ? att_prev[b * T_ + ti] : 0.0f;
    }
    for (int i = tid; i < C_ * KW; i += 256) s_w[i] = conv_w[i];
    __syncthreads();
    int t = t0 + tid;
    if (t < T_) {
        float acc[C_];
#pragma unroll
        for (int c = 0; c < C_; ++c) acc[c] = 0.0f;
        for (int j = 0; j < KW; ++j) {
            float a = s_att[tid + j];
#pragma unroll
            for (int c = 0; c < C_; ++c) acc[c] += a * s_w[c * KW + j];
        }
        bf16* dst = convpad + (size_t)(b * T_ + t) * 32;
#pragma unroll
        for (int c = 0; c < C_; ++c) dst[c] = (bf16)acc[c];
#pragma unroll
        for (int c = C_; c < 32; ++c) dst[c] = (bf16)0.0f;
    }
}

// ---------------- main fused GEMM, N-split x2 ----------------
// grid 750: bid = rc*2 + nh. Block: 128 rows x 256 n (16 nt), K'=544.
// A-frags in regs; B double-buffered LDS (k-major, conflict-free); bias/gvec in LDS.
// e partial = gsum[nh] - 2*sum gv*u, atomically added into zeroed e_out.
__global__ __launch_bounds__(256, 2) void main_gemm(
        const float* __restrict__ enc, const bf16* __restrict__ convpad,
        const bf16* __restrict__ wt2, const float* __restrict__ biasC,
        const float* __restrict__ gvec, const float* __restrict__ gsum,
        float* __restrict__ e_out) {
    __shared__ __align__(16) char b_lds[2 * BT_BYTES];   // 34816 B
    __shared__ float biasL[2][256];
    __shared__ float gvL[256];
    const int tid  = threadIdx.x;
    const int lane = tid & 63;
    const int wid  = tid >> 6;
    const int g    = lane >> 4;       // 0..3 (k-group / D row-group)
    const int c15  = lane & 15;       // A-row / B-col within tile
    const int bid  = blockIdx.x;
    const int nh   = bid & 1;         // n-half
    const int rc   = bid >> 1;        // row chunk
    const int rowbase = rc * 128 + wid * 32;
    const int nbase   = nh * 256;

    // stage bias/gvec slices into LDS (covered by loop-top __syncthreads)
    {
        int b0 = (rc * 128) / T_, b1 = (rc * 128 + 127) / T_;
        biasL[0][tid] = biasC[b0 * 512 + nbase + tid];
        biasL[1][tid] = biasC[b1 * 512 + nbase + tid];
        gvL[tid]      = gvec[nbase + tid];
    }

    // ---- A-frags: 2 tiles x 16 ksteps, global f32 -> bf16 regs (ALL static idx) ----
    bf16x8 afrag[2][16];
#pragma unroll
    for (int m = 0; m < 2; ++m) {
        const float* ap = enc + (size_t)(rowbase + m * 16 + c15) * 512 + g * 8;
#pragma unroll
        for (int kt = 0; kt < 16; ++kt) {
            float4 f0 = *(const float4*)(ap + kt * 32);
            float4 f1 = *(const float4*)(ap + kt * 32 + 4);
            bf16x8 v;
            v[0] = (bf16)f0.x; v[1] = (bf16)f0.y; v[2] = (bf16)f0.z; v[3] = (bf16)f0.w;
            v[4] = (bf16)f1.x; v[5] = (bf16)f1.y; v[6] = (bf16)f1.z; v[7] = (bf16)f1.w;
            afrag[m][kt] = v;
        }
    }
    // conv A-frags (k-slot 16)
    bf16x8 acv[2];
#pragma unroll
    for (int m = 0; m < 2; ++m)
        acv[m] = *(const bf16x8*)(convpad + (size_t)(rowbase + m * 16 + c15) * 32 + g * 8);

    // batch-select offsets into biasL (flattened [2][256]) for D rows
    int bsel[2][4];
    {
        int b0lim = ((rc * 128) / T_ + 1) * T_;
#pragma unroll
        for (int m = 0; m < 2; ++m)
#pragma unroll
            for (int r = 0; r < 4; ++r)
                bsel[m][r] = (rowbase + m * 16 + g * 4 + r >= b0lim) ? 256 : 0;
    }

    // ---- stage B tile 0 of this half into buf 0 ----
    {
        const char* src = (const char*)wt2 + (size_t)(nh * 16) * BT_BYTES;
#pragma unroll
        for (int p = 0; p < 4; ++p) {
            int q = wid + p * 4;
            load_lds16(src + q * 1024 + lane * 16, b_lds + q * 1024);
        }
        if (wid == 0) load_lds16(src + 16 * 1024 + lane * 16, b_lds + 16 * 1024);
    }

    const int lane_off = g * 256 + c15 * 16;
    const float* blf = &biasL[0][0];
    float su[2][4] = {{0.f,0.f,0.f,0.f},{0.f,0.f,0.f,0.f}};

    for (int nt = 0; nt < 16; ++nt) {
        __syncthreads();   // B[nt] resident; all waves done with B[nt-1]
        if (nt < 15) {
            const char* src = (const char*)wt2 + (size_t)(nh * 16 + nt + 1) * BT_BYTES;
            char* dst = b_lds + ((nt + 1) & 1) * BT_BYTES;
#pragma unroll
            for (int p = 0; p < 4; ++p) {
                int q = wid + p * 4;
                load_lds16(src + q * 1024 + lane * 16, dst + q * 1024);
            }
            if (wid == 0) load_lds16(src + 16 * 1024 + lane * 16, dst + 16 * 1024);
        }
        const char* bb = b_lds + (nt & 1) * BT_BYTES + lane_off;
        f32x4 acc0 = {0.f, 0.f, 0.f, 0.f};
        f32x4 acc1 = {0.f, 0.f, 0.f, 0.f};
#pragma unroll
        for (int kt = 0; kt < 16; ++kt) {
            bf16x8 bv = *(const bf16x8*)(bb + kt * 1024);
            acc0 = __builtin_amdgcn_mfma_f32_16x16x32_bf16(afrag[0][kt], bv, acc0, 0, 0, 0);
            acc1 = __builtin_amdgcn_mfma_f32_16x16x32_bf16(afrag[1][kt], bv, acc1, 0, 0, 0);
        }
        {   // conv k-slot
            bf16x8 bv = *(const bf16x8*)(bb + 16 * 1024);
            acc0 = __builtin_amdgcn_mfma_f32_16x16x32_bf16(acv[0], bv, acc0, 0, 0, 0);
            acc1 = __builtin_amdgcn_mfma_f32_16x16x32_bf16(acv[1], bv, acc1, 0, 0, 0);
        }
        int nloc = nt * 16 + c15;
        float gv = gvL[nloc];
        // tanh(x) = 1 - 2u, u = 1/(2^(x*2log2e)+1); accumulate gv*u only
#pragma unroll
        for (int m = 0; m < 2; ++m) {
            f32x4 a = m ? acc1 : acc0;
#pragma unroll
            for (int r = 0; r < 4; ++r) {
                float t  = fmaf(a[r], C2L, blf[bsel[m][r] + nloc]);
                float ex = exp2f(t);
                float u  = __builtin_amdgcn_rcpf(ex + 1.0f);
                su[m][r] = fmaf(gv, u, su[m][r]);
            }
        }
    }
    // reduce su over the 16 c15-lanes sharing the same D rows
#pragma unroll
    for (int msk = 1; msk < 16; msk <<= 1)
#pragma unroll
        for (int m = 0; m < 2; ++m)
#pragma unroll
            for (int r = 0; r < 4; ++r)
                su[m][r] += __shfl_xor(su[m][r], msk, 64);
    if (c15 == 0) {
        float gs = gsum[nh];
#pragma unroll
        for (int m = 0; m < 2; ++m)
#pragma unroll
            for (int r = 0; r < 4; ++r)
                atomicAdd(e_out + rowbase + m * 16 + g * 4 + r,
                          gs - 2.0f * su[m][r]);
    }
}

// ---------------- softmax over T per batch: w = softmax(SCALING * e) ----------------
__global__ void softmax_k(const float* __restrict__ e_in, float* __restrict__ w_out) {
    int b = blockIdx.x, tid = threadIdx.x;
    __shared__ float red[256];
    float v[6];
    float mx = -1e30f;
#pragma unroll
    for (int i = 0; i < 6; ++i) {
        int t = i * 256 + tid;
        v[i] = (t < T_) ? SCALING_ * e_in[b * T_ + t] : -1e30f;
        mx = fmaxf(mx, v[i]);
    }
    red[tid] = mx; __syncthreads();
    for (int st = 128; st > 0; st >>= 1) {
        if (tid < st) red[tid] = fmaxf(red[tid], red[tid + st]);
        __syncthreads();
    }
    mx = red[0]; __syncthreads();
    float sum = 0.f;
#pragma unroll
    for (int i = 0; i < 6; ++i) { v[i] = __expf(v[i] - mx); sum += v[i]; }
    red[tid] = sum; __syncthreads();
    for (int st = 128; st > 0; st >>= 1) {
        if (tid < st) red[tid] += red[tid + st];
        __syncthreads();
    }
    float inv = 1.0f / red[0];
#pragma unroll
    for (int i = 0; i < 6; ++i) {
        int t = i * 256 + tid;
        if (t < T_) w_out[b * T_ + t] = v[i] * inv;
    }
}

// ---------------- context partial ----------------
__global__ void ctx_partial(const float* __restrict__ enc, const float* __restrict__ w,
                            float* __restrict__ partial) {
    int e  = blockIdx.x * 256 + threadIdx.x;   // gridDim.x = 2
    int ty = blockIdx.y;                        // 16
    int b  = blockIdx.z;                        // 32
    int t0 = ty * 94;
    int t1 = min(t0 + 94, T_);
    float acc = 0.f;
#pragma unroll 8
    for (int t = t0; t < t1; ++t)
        acc += w[b * T_ + t] * enc[((size_t)b * T_ + t) * 512 + e];
    partial[(ty * 32 + b) * 512 + e] = acc;
}

// ---------------- output proj: c[b] = (sum partials) @ W_o + b_o ----------------
__global__ void out_proj(const float* __restrict__ partial, const float* __restrict__ Wo,
                         const float* __restrict__ bo, float* __restrict__ out) {
    int b = blockIdx.x, half = blockIdx.y, tid = threadIdx.x;
    __shared__ float ctx[512];
    for (int e = tid; e < 512; e += 256) {
        float s = 0.f;
#pragma unroll
        for (int p = 0; p < 16; ++p) s += partial[(p * 32 + b) * 512 + e];
        ctx[e] = s;
    }
    __syncthreads();
    int o = half * 256 + tid;
    float a0 = bo[o];
#pragma unroll 8
    for (int e = 0; e < 512; ++e)
        a0 += ctx[e] * Wo[e * 512 + o];
    out[b * 512 + o] = a0;
}

extern "C" void kernel_launch(void* const* d_in, const int* in_sizes, int n_in,
                              void* d_out, int out_size, void* d_ws, size_t ws_size,
                              hipStream_t stream) {
    const float* enc      = (const float*)d_in[0];
    const float* dec_z    = (const float*)d_in[2];
    const float* att_prev = (const float*)d_in[3];
    const float* W_enc    = (const float*)d_in[4];
    const float* b_enc    = (const float*)d_in[5];
    const float* W_dec    = (const float*)d_in[6];
    const float* W_att    = (const float*)d_in[7];
    const float* conv_w   = (const float*)d_in[8];
    const float* gvec     = (const float*)d_in[9];
    const float* W_o      = (const float*)d_in[10];
    const float* b_o      = (const float*)d_in[11];

    // workspace layout (bytes); partial aliases biasC+e_buf (dead by ctx_partial time):
    //   [0, 65536)             biasC    f32 [32][512]
    //   [65536, 257536)        e_buf    f32 [48000]
    //   [257536, 257544)       gsum     f32 [2]
    //   [0, 1048576)           partial  f32 [16][32][512]  (after biasC/e_buf dead)
    //   [1048576, 4120576)     convpad  bf16 [48000][32]
    //   [4120576, 4677632)     wt2      bf16 [32][68][16][8]
    char* ws = (char*)d_ws;
    float* biasC   = (float*)(ws);
    float* e_buf   = (float*)(ws + 65536);
    float* gsum    = (float*)(ws + 257536);
    float* partial = (float*)(ws);
    bf16*  convpad = (bf16*)(ws + 1048576);
    bf16*  wt2     = (bf16*)(ws + 4120576);

    float* c_out = (float*)d_out;           // [32][512]
    float* w_out = c_out + B_ * 512;        // [32][1500]

    prep_bias<<<64, 256, 0, stream>>>(dec_z, W_dec, b_enc, biasC);
    gsum_k<<<2, 256, 0, stream>>>(gvec, gsum);
    prep_wt<<<KP, 256, 0, stream>>>(W_enc, W_att, wt2);
    prep_conv<<<dim3(6, B_), 256, 0, stream>>>(att_prev, conv_w, convpad);
    hipMemsetAsync(e_buf, 0, M_ * sizeof(float), stream);
    main_gemm<<<750, 256, 0, stream>>>(enc, convpad, wt2, biasC, gvec, gsum, e_buf);
    softmax_k<<<B_, 256, 0, stream>>>(e_buf, w_out);
    ctx_partial<<<dim3(2, 16, B_), 256, 0, stream>>>(enc, w_out, partial);
    out_proj<<<dim3(B_, 2), 256, 0, stream>>>(partial, W_o, b_o, c_out);
}

// Round 6
// 311.242 us; speedup vs baseline: 1.7393x; 1.0171x over previous
//
#include <hip/hip_runtime.h>
#include <hip/hip_bf16.h>

// Problem constants
#define B_  32
#define T_  1500
#define C_  10
#define KH  100      // conv half-width
#define KW  201      // conv width
#define M_  48000
#define KP  544      // K' = 512 (enc) + 32 (conv padded)
#define SCALING_ 2.0f
#define BT_BYTES 17408   // one staged B tile: 16 cols x 544 k x 2B (k-major chunks)
#define C2L 2.8853900817779268f   // 2*log2(e)

typedef __bf16 bf16;
typedef __attribute__((ext_vector_type(8))) __bf16 bf16x8;
typedef __attribute__((ext_vector_type(4))) float f32x4;

__device__ __forceinline__ void load_lds16(const void* g, void* l) {
    __builtin_amdgcn_global_load_lds(
        (const __attribute__((address_space(1))) unsigned int*)g,
        (__attribute__((address_space(3))) unsigned int*)l,
        16, 0, 0);
}

// ============ fused prep: [0,64) bias | [64,200) wt permute | [200,392) conv ============
__global__ void fused_prep(const float* __restrict__ dec_z, const float* __restrict__ W_dec,
                           const float* __restrict__ b_enc, float* __restrict__ biasC,
                           const float* __restrict__ W_enc, const float* __restrict__ W_att,
                           bf16* __restrict__ wt2,
                           const float* __restrict__ att_prev, const float* __restrict__ conv_w,
                           bf16* __restrict__ convpad) {
    __shared__ float smem[2466];   // conv branch: s_att[456] + s_w[2010]
    const int bid = blockIdx.x;
    const int tid = threadIdx.x;

    if (bid < 64) {
        // ---- biasC[b][a] = (b_enc[a] + dec_z[b,:] @ W_dec[:,a]) * 2log2e ----
        int idx = bid * 256 + tid;   // [0, 16384)
        int b = idx >> 9, a = idx & 511;
        float acc = b_enc[a];
#pragma unroll 16
        for (int d = 0; d < 512; ++d)
            acc += dec_z[b * 512 + d] * W_dec[d * 512 + a];
        biasC[idx] = acc * C2L;
    } else if (bid < 200) {
        // ---- wt2 k-major permute: chunk idx -> (nt,s,c); thread writes 8 k's (16B) ----
        int idx = (bid - 64) * 256 + tid;   // [0, 34816)
        int nt = idx / 1088;
        int rem = idx - nt * 1088;
        int s = rem >> 4, c = rem & 15;
        int a = nt * 16 + c;
        bf16x8 vv;
#pragma unroll
        for (int j = 0; j < 8; ++j) {
            int k = s * 8 + j;
            float v;
            if (k < 512)       v = W_enc[k * 512 + a];
            else if (k < 522)  v = W_att[(k - 512) * 512 + a];
            else               v = 0.0f;
            vv[j] = (bf16)v;
        }
        *(bf16x8*)(wt2 + (size_t)idx * 8) = vv;
    } else {
        // ---- convpad[row][0..9] = conv(att_prev)[b,:,t], rest of 32 = 0 ----
        int cb = bid - 200;           // [0, 192)
        int tc = cb % 6, b = cb / 6;
        float* s_att = smem;          // 456
        float* s_w   = smem + 456;    // 2010
        int t0 = tc * 256;
        for (int i = tid; i < 456; i += 256) {
            int ti = t0 - KH + i;
            s_att[i] = (ti >= 0 && ti < T_) ? att_prev[b * T_ + ti] : 0.0f;
        }
        for (int i = tid; i < C_ * KW; i += 256) s_w[i] = conv_w[i];
        __syncthreads();
        int t = t0 + tid;
        if (t < T_) {
            float acc[C_];
#pragma unroll
            for (int c = 0; c < C_; ++c) acc[c] = 0.0f;
            for (int j = 0; j < KW; ++j) {
                float a = s_att[tid + j];
#pragma unroll
                for (int c = 0; c < C_; ++c) acc[c] += a * s_w[c * KW + j];
            }
            bf16* dst = convpad + (size_t)(b * T_ + t) * 32;
#pragma unroll
            for (int c = 0; c < C_; ++c) dst[c] = (bf16)acc[c];
#pragma unroll
            for (int c = C_; c < 32; ++c) dst[c] = (bf16)0.0f;
        }
    }
}

// ---------------- main fused GEMM, N-split x2 ----------------
// grid 750: bid = rc*2 + nh. Block: 128 rows x 256 n (16 nt), K'=544.
// A-frags in regs (no spill at 170-reg cap); B double-buffered LDS (k-major,
// conflict-free). Stores su = sum gv*u per half; softmax shift-invariance drops
// the gsum constant, so no atomics/memset needed.
__global__ __launch_bounds__(256, 3) void main_gemm(
        const float* __restrict__ enc, const bf16* __restrict__ convpad,
        const bf16* __restrict__ wt2, const float* __restrict__ biasC,
        const float* __restrict__ gvec, float* __restrict__ e_part) {
    __shared__ __align__(16) char b_lds[2 * BT_BYTES];   // 34816 B
    __shared__ float biasL[2][256];
    __shared__ float gvL[256];
    const int tid  = threadIdx.x;
    const int lane = tid & 63;
    const int wid  = tid >> 6;
    const int g    = lane >> 4;       // 0..3 (k-group / D row-group)
    const int c15  = lane & 15;       // A-row / B-col within tile
    const int bid  = blockIdx.x;
    const int nh   = bid & 1;         // n-half
    const int rc   = bid >> 1;        // row chunk
    const int rowbase = rc * 128 + wid * 32;
    const int nbase   = nh * 256;

    // stage bias/gvec slices into LDS (covered by loop-top __syncthreads)
    {
        int b0 = (rc * 128) / T_, b1 = (rc * 128 + 127) / T_;
        biasL[0][tid] = biasC[b0 * 512 + nbase + tid];
        biasL[1][tid] = biasC[b1 * 512 + nbase + tid];
        gvL[tid]      = gvec[nbase + tid];
    }

    // ---- A-frags: 2 tiles x 16 ksteps, global f32 -> bf16 regs (ALL static idx) ----
    bf16x8 afrag[2][16];
#pragma unroll
    for (int m = 0; m < 2; ++m) {
        const float* ap = enc + (size_t)(rowbase + m * 16 + c15) * 512 + g * 8;
#pragma unroll
        for (int kt = 0; kt < 16; ++kt) {
            float4 f0 = *(const float4*)(ap + kt * 32);
            float4 f1 = *(const float4*)(ap + kt * 32 + 4);
            bf16x8 v;
            v[0] = (bf16)f0.x; v[1] = (bf16)f0.y; v[2] = (bf16)f0.z; v[3] = (bf16)f0.w;
            v[4] = (bf16)f1.x; v[5] = (bf16)f1.y; v[6] = (bf16)f1.z; v[7] = (bf16)f1.w;
            afrag[m][kt] = v;
        }
    }
    // conv A-frags (k-slot 16)
    bf16x8 acv[2];
#pragma unroll
    for (int m = 0; m < 2; ++m)
        acv[m] = *(const bf16x8*)(convpad + (size_t)(rowbase + m * 16 + c15) * 32 + g * 8);

    // batch-select offsets into biasL (flattened [2][256]) for D rows
    int bsel[2][4];
    {
        int b0lim = ((rc * 128) / T_ + 1) * T_;
#pragma unroll
        for (int m = 0; m < 2; ++m)
#pragma unroll
            for (int r = 0; r < 4; ++r)
                bsel[m][r] = (rowbase + m * 16 + g * 4 + r >= b0lim) ? 256 : 0;
    }

    // ---- stage B tile 0 of this half into buf 0 ----
    {
        const char* src = (const char*)wt2 + (size_t)(nh * 16) * BT_BYTES;
#pragma unroll
        for (int p = 0; p < 4; ++p) {
            int q = wid + p * 4;
            load_lds16(src + q * 1024 + lane * 16, b_lds + q * 1024);
        }
        if (wid == 0) load_lds16(src + 16 * 1024 + lane * 16, b_lds + 16 * 1024);
    }

    const int lane_off = g * 256 + c15 * 16;
    const float* blf = &biasL[0][0];
    float su[2][4] = {{0.f,0.f,0.f,0.f},{0.f,0.f,0.f,0.f}};

    for (int nt = 0; nt < 16; ++nt) {
        __syncthreads();   // B[nt] resident; all waves done with B[nt-1]
        if (nt < 15) {
            const char* src = (const char*)wt2 + (size_t)(nh * 16 + nt + 1) * BT_BYTES;
            char* dst = b_lds + ((nt + 1) & 1) * BT_BYTES;
#pragma unroll
            for (int p = 0; p < 4; ++p) {
                int q = wid + p * 4;
                load_lds16(src + q * 1024 + lane * 16, dst + q * 1024);
            }
            if (wid == 0) load_lds16(src + 16 * 1024 + lane * 16, dst + 16 * 1024);
        }
        const char* bb = b_lds + (nt & 1) * BT_BYTES + lane_off;
        f32x4 acc0 = {0.f, 0.f, 0.f, 0.f};
        f32x4 acc1 = {0.f, 0.f, 0.f, 0.f};
#pragma unroll
        for (int kt = 0; kt < 16; ++kt) {
            bf16x8 bv = *(const bf16x8*)(bb + kt * 1024);
            acc0 = __builtin_amdgcn_mfma_f32_16x16x32_bf16(afrag[0][kt], bv, acc0, 0, 0, 0);
            acc1 = __builtin_amdgcn_mfma_f32_16x16x32_bf16(afrag[1][kt], bv, acc1, 0, 0, 0);
        }
        {   // conv k-slot
            bf16x8 bv = *(const bf16x8*)(bb + 16 * 1024);
            acc0 = __builtin_amdgcn_mfma_f32_16x16x32_bf16(acv[0], bv, acc0, 0, 0, 0);
            acc1 = __builtin_amdgcn_mfma_f32_16x16x32_bf16(acv[1], bv, acc1, 0, 0, 0);
        }
        int nloc = nt * 16 + c15;
        float gv = gvL[nloc];
        // tanh(x) = 1 - 2u, u = 1/(2^(x*2log2e)+1); accumulate gv*u only
#pragma unroll
        for (int m = 0; m < 2; ++m) {
            f32x4 a = m ? acc1 : acc0;
#pragma unroll
            for (int r = 0; r < 4; ++r) {
                float t  = fmaf(a[r], C2L, blf[bsel[m][r] + nloc]);
                float ex = exp2f(t);
                float u  = __builtin_amdgcn_rcpf(ex + 1.0f);
                su[m][r] = fmaf(gv, u, su[m][r]);
            }
        }
    }
    // reduce su over the 16 c15-lanes sharing the same D rows
#pragma unroll
    for (int msk = 1; msk < 16; msk <<= 1)
#pragma unroll
        for (int m = 0; m < 2; ++m)
#pragma unroll
            for (int r = 0; r < 4; ++r)
                su[m][r] += __shfl_xor(su[m][r], msk, 64);
    if (c15 == 0) {
#pragma unroll
        for (int m = 0; m < 2; ++m)
#pragma unroll
            for (int r = 0; r < 4; ++r)
                e_part[nh * M_ + rowbase + m * 16 + g * 4 + r] = su[m][r];
    }
}

// ---------------- softmax over T per batch: w = softmax(-2*S*(su0+su1)) ----------------
// (softmax shift-invariance: e = G - 2*(su0+su1); the constant G drops out)
__global__ void softmax_k(const float* __restrict__ e_part, float* __restrict__ w_out) {
    int b = blockIdx.x, tid = threadIdx.x;
    __shared__ float red[256];
    float v[6];
    float mx = -1e30f;
#pragma unroll
    for (int i = 0; i < 6; ++i) {
        int t = i * 256 + tid;
        if (t < T_) {
            float s2 = e_part[b * T_ + t] + e_part[M_ + b * T_ + t];
            v[i] = -2.0f * SCALING_ * s2;
        } else v[i] = -1e30f;
        mx = fmaxf(mx, v[i]);
    }
    red[tid] = mx; __syncthreads();
    for (int st = 128; st > 0; st >>= 1) {
        if (tid < st) red[tid] = fmaxf(red[tid], red[tid + st]);
        __syncthreads();
    }
    mx = red[0]; __syncthreads();
    float sum = 0.f;
#pragma unroll
    for (int i = 0; i < 6; ++i) { v[i] = __expf(v[i] - mx); sum += v[i]; }
    red[tid] = sum; __syncthreads();
    for (int st = 128; st > 0; st >>= 1) {
        if (tid < st) red[tid] += red[tid + st];
        __syncthreads();
    }
    float inv = 1.0f / red[0];
#pragma unroll
    for (int i = 0; i < 6; ++i) {
        int t = i * 256 + tid;
        if (t < T_) w_out[b * T_ + t] = v[i] * inv;
    }
}

// ---------------- context partial: float4 lanes, 2-way t-interleave per block ----------
__global__ void ctx_partial(const float* __restrict__ enc, const float* __restrict__ w,
                            float* __restrict__ partial) {
    int ty = blockIdx.x;      // 16
    int b  = blockIdx.y;      // 32
    int tid = threadIdx.x;
    int half = tid >> 7;      // 0/1: t-interleave
    int cq   = tid & 127;     // float4 column group
    int t0 = ty * 94;
    int t1 = min(t0 + 94, T_);
    f32x4 acc = {0.f, 0.f, 0.f, 0.f};
    for (int t = t0 + half; t < t1; t += 2) {
        float wt = w[b * T_ + t];
        f32x4 ev = *(const f32x4*)(enc + ((size_t)(b * T_ + t) << 9) + cq * 4);
        acc.x = fmaf(wt, ev.x, acc.x);
        acc.y = fmaf(wt, ev.y, acc.y);
        acc.z = fmaf(wt, ev.z, acc.z);
        acc.w = fmaf(wt, ev.w, acc.w);
    }
    __shared__ f32x4 red[256];
    red[tid] = acc;
    __syncthreads();
    if (tid < 128) {
        f32x4 s = red[tid];
        f32x4 o = red[tid + 128];
        s.x += o.x; s.y += o.y; s.z += o.z; s.w += o.w;
        *(f32x4*)(partial + ((size_t)(ty * 32 + b) << 9) + tid * 4) = s;
    }
}

// ---------------- output proj: c[b] = (sum partials) @ W_o + b_o ----------------
__global__ void out_proj(const float* __restrict__ partial, const float* __restrict__ Wo,
                         const float* __restrict__ bo, float* __restrict__ out) {
    int b = blockIdx.x, half = blockIdx.y, tid = threadIdx.x;
    __shared__ float ctx[512];
    if (tid < 128) {
        f32x4 s = {0.f, 0.f, 0.f, 0.f};
#pragma unroll
        for (int p = 0; p < 16; ++p) {
            f32x4 v = *(const f32x4*)(partial + ((size_t)(p * 32 + b) << 9) + tid * 4);
            s.x += v.x; s.y += v.y; s.z += v.z; s.w += v.w;
        }
        *(f32x4*)(ctx + tid * 4) = s;
    }
    __syncthreads();
    int o = half * 256 + tid;
    float a0 = bo[o];
#pragma unroll 16
    for (int e = 0; e < 512; ++e)
        a0 += ctx[e] * Wo[e * 512 + o];
    out[b * 512 + o] = a0;
}

extern "C" void kernel_launch(void* const* d_in, const int* in_sizes, int n_in,
                              void* d_out, int out_size, void* d_ws, size_t ws_size,
                              hipStream_t stream) {
    const float* enc      = (const float*)d_in[0];
    const float* dec_z    = (const float*)d_in[2];
    const float* att_prev = (const float*)d_in[3];
    const float* W_enc    = (const float*)d_in[4];
    const float* b_enc    = (const float*)d_in[5];
    const float* W_dec    = (const float*)d_in[6];
    const float* W_att    = (const float*)d_in[7];
    const float* conv_w   = (const float*)d_in[8];
    const float* gvec     = (const float*)d_in[9];
    const float* W_o      = (const float*)d_in[10];
    const float* b_o      = (const float*)d_in[11];

    // workspace layout (bytes); partial aliases biasC+e_part (dead by ctx time):
    //   [0, 65536)             biasC    f32 [32][512]
    //   [65536, 449536)        e_part   f32 [2][48000]
    //   [0, 1048576)           partial  f32 [16][32][512]  (after biasC/e_part dead)
    //   [1048576, 4120576)     convpad  bf16 [48000][32]
    //   [4120576, 4677632)     wt2      bf16 [32][68][16][8]
    char* ws = (char*)d_ws;
    float* biasC   = (float*)(ws);
    float* e_part  = (float*)(ws + 65536);
    float* partial = (float*)(ws);
    bf16*  convpad = (bf16*)(ws + 1048576);
    bf16*  wt2     = (bf16*)(ws + 4120576);

    float* c_out = (float*)d_out;           // [32][512]
    float* w_out = c_out + B_ * 512;        // [32][1500]

    fused_prep<<<392, 256, 0, stream>>>(dec_z, W_dec, b_enc, biasC,
                                        W_enc, W_att, wt2,
                                        att_prev, conv_w, convpad);
    main_gemm<<<750, 256, 0, stream>>>(enc, convpad, wt2, biasC, gvec, e_part);
    softmax_k<<<B_, 256, 0, stream>>>(e_part, w_out);
    ctx_partial<<<dim3(16, B_), 256, 0, stream>>>(enc, w_out, partial);
    out_proj<<<dim3(B_, 2), 256, 0, stream>>>(partial, W_o, b_o, c_out);
}